// Round 2
// baseline (181.122 us; speedup 1.0000x reference)
//
#include <hip/hip_runtime.h>
#include <hip/hip_bf16.h>
#include <stdint.h>

// ---------------------------------------------------------------------------
// SupervisedContrastiveLoss, B=4096, D=1024, C=32, T=0.1, eps=1e-8
// out = (1/B) * sum_i [ log(denom_i)*W_i - S_i ]
//   denom_i = sum_{j!=i} exp(Z_ij)            (needs full Z -> fused MFMA GEMM)
//   W_i     = (classCount[l_i]-1) + pw*(sl_i . colsum(SL))
//   S_i     = sum_j Z_ij*pos_ij + pw*10*(sl_i . rnG_i),  rnG = rn@(rn^T@SL)
// Z symmetric -> only upper-triangular 128x128 tiles (528 blocks), row+col sums.
// R1: gemm staging via global_load_lds width=16 (m97 structure), XOR swizzle
//     moved to the GLOBAL source side (LDS writes linear lane*16).
// ---------------------------------------------------------------------------

typedef float f32x4 __attribute__((ext_vector_type(4)));
typedef __bf16 bf16x8 __attribute__((ext_vector_type(8)));
typedef unsigned short u16x8 __attribute__((ext_vector_type(8)));

#define INV_T 10.0f

#define GLD16(gp, lp)                                                          \
    __builtin_amdgcn_global_load_lds(                                          \
        (const __attribute__((address_space(1))) uint32_t*)(gp),               \
        (__attribute__((address_space(3))) uint32_t*)(lp), 16, 0, 0)

// workspace layout (bytes)
#define OFF_RNBF  0                         // 4096*1024*2 = 8388608
#define OFF_DENOM 8388608                   // 4096*4
#define OFF_POSS  (OFF_DENOM + 16384)
#define OFF_G     (OFF_POSS + 16384)        // 1024*32*4 = 131072
#define OFF_CSUM  (OFF_G + 131072)          // 32*4 (+pad)
#define OFF_CCNT  (OFF_CSUM + 128)
#define OFF_OACC  (OFF_CCNT + 128)          // double
#define OFF_RNG   (OFF_OACC + 16)           // 4096*32*4 = 524288
#define WS_END    (OFF_RNG + 524288)
#define ZERO_BYTES (WS_END - OFF_DENOM)

// ---------------- normalize rows -> bf16 ----------------
__global__ __launch_bounds__(256) void scl_normalize(const float* __restrict__ rep,
                                                     uint16_t* __restrict__ rnbf) {
    int row = blockIdx.x;
    int t = threadIdx.x;
    const float4* src = reinterpret_cast<const float4*>(rep + (size_t)row * 1024);
    float4 v = src[t];
    float s = v.x * v.x + v.y * v.y + v.z * v.z + v.w * v.w;
#pragma unroll
    for (int m = 1; m < 64; m <<= 1) s += __shfl_xor(s, m, 64);
    __shared__ float red[4];
    if ((t & 63) == 0) red[t >> 6] = s;
    __syncthreads();
    s = red[0] + red[1] + red[2] + red[3];
    float nf = 1.0f / fmaxf(sqrtf(s), 1e-8f);
    ushort4 o;
    o.x = __builtin_bit_cast(unsigned short, (__bf16)(v.x * nf));
    o.y = __builtin_bit_cast(unsigned short, (__bf16)(v.y * nf));
    o.z = __builtin_bit_cast(unsigned short, (__bf16)(v.z * nf));
    o.w = __builtin_bit_cast(unsigned short, (__bf16)(v.w * nf));
    reinterpret_cast<ushort4*>(rnbf + (size_t)row * 1024)[t] = o;
}

// ---------------- colsum of soft_labels + class histogram ----------------
__global__ __launch_bounds__(256) void scl_prep(const float* __restrict__ sl,
                                                const int* __restrict__ labels,
                                                float* __restrict__ csum,
                                                int* __restrict__ ccnt) {
    __shared__ float part[8][32];
    __shared__ int bins[32];
    int t = threadIdx.x, b = blockIdx.x;
    if (t < 32) bins[t] = 0;
    __syncthreads();
    if (t < 128) atomicAdd(&bins[labels[b * 128 + t]], 1);
    int c = t & 31, rg = t >> 5;
    float s = 0.f;
#pragma unroll 4
    for (int k = 0; k < 16; ++k) {
        int i = b * 128 + rg * 16 + k;
        s += sl[i * 32 + c];
    }
    part[rg][c] = s;
    __syncthreads();
    if (t < 32) {
        float tot = 0.f;
#pragma unroll
        for (int g = 0; g < 8; ++g) tot += part[g][t];
        atomicAdd(&csum[t], tot);
        atomicAdd(&ccnt[t], bins[t]);
    }
}

// ---------------- G = rn^T @ SL  [1024 x 32], split-K with atomics ----------------
__global__ __launch_bounds__(256) void scl_G(const uint16_t* __restrict__ rnbf,
                                             const float* __restrict__ sl,
                                             float* __restrict__ G) {
    int t = threadIdx.x;
    int dblk = blockIdx.x & 31, ks = blockIdx.x >> 5;  // 32 d-blocks x 16 k-splits
    int dl = t >> 3, cq = t & 7;
    int d = dblk * 32 + dl;
    const f32x4* sl4 = (const f32x4*)sl;
    f32x4 acc = {0.f, 0.f, 0.f, 0.f};
    int i0 = ks * 256;
#pragma unroll 4
    for (int k = 0; k < 256; ++k) {
        int i = i0 + k;
        float v = (float)__builtin_bit_cast(__bf16, rnbf[(size_t)i * 1024 + d]);
        f32x4 w = sl4[i * 8 + cq];
        acc += w * v;
    }
    float* gp = &G[d * 32 + cq * 4];
    atomicAdd(gp + 0, acc[0]);
    atomicAdd(gp + 1, acc[1]);
    atomicAdd(gp + 2, acc[2]);
    atomicAdd(gp + 3, acc[3]);
}

// ---------------- rnG = rn @ G  [4096 x 32], split-D with atomics ----------------
__global__ __launch_bounds__(256) void scl_rnG(const uint16_t* __restrict__ rnbf,
                                               const float* __restrict__ G,
                                               float* __restrict__ rnG) {
    int t = threadIdx.x;
    int dh = t >> 7;          // 0..1 (d-halves)
    int r = (t >> 3) & 15;    // row within block
    int cq = t & 7;
    int row = blockIdx.x * 16 + r;
    const f32x4* G4 = (const f32x4*)G;
    const u16x8* rn8 = (const u16x8*)(rnbf + (size_t)row * 1024);
    f32x4 acc = {0.f, 0.f, 0.f, 0.f};
    int d80 = dh * 64;
#pragma unroll 2
    for (int d8 = 0; d8 < 64; ++d8) {
        u16x8 rv = rn8[d80 + d8];
#pragma unroll
        for (int j = 0; j < 8; ++j) {
            float v = (float)__builtin_bit_cast(__bf16, (unsigned short)rv[j]);
            acc += G4[((d80 + d8) * 8 + j) * 8 + cq] * v;
        }
    }
    float* op = &rnG[row * 32 + cq * 4];
    atomicAdd(op + 0, acc[0]);
    atomicAdd(op + 1, acc[1]);
    atomicAdd(op + 2, acc[2]);
    atomicAdd(op + 3, acc[3]);
}

// ---------------- main fused GEMM: rowsum/colsum of exp(Z) and pos*Z ----------------
// m97 structure: global_load_lds(16B) staging, 2-barrier K-loop.
// Swizzle on the GLOBAL side: lane l fetches chunk c=(l&7)^(l>>3) of row r0+(l>>3);
// HW writes lane l at ldsbase + l*16 -> chunk lands at slot c^(r&7) (read side below).
__global__ __launch_bounds__(256) void scl_gemm(const uint16_t* __restrict__ rnbf,
                                                const int* __restrict__ labels,
                                                float* __restrict__ denom,
                                                float* __restrict__ posS) {
    __shared__ __align__(16) uint16_t As[128 * 64];
    __shared__ __align__(16) uint16_t Bs[128 * 64];
    __shared__ int lblA[128], lblB[128];

    // upper-triangular tile decode: block L -> (bi <= bj)
    int L = blockIdx.x;
    int bi = 0, rem = L;
    while (rem >= 32 - bi) { rem -= 32 - bi; ++bi; }
    int bj = bi + rem;
    int rowA0 = bi * 128, colB0 = bj * 128;

    int tid = threadIdx.x;
    if (tid < 128) {
        lblA[tid] = labels[rowA0 + tid];
        lblB[tid] = labels[colB0 + tid];
    }

    int lane = tid & 63, warp = tid >> 6;
    int wr = warp >> 1, wc = warp & 1;
    int m_ = lane & 15, g = lane >> 4;

    // staging source pointers (per lane), swizzled chunk on the global side
    int rsub = lane >> 3;               // 0..7 (row within 8-row group = r&7)
    int csw = (lane & 7) ^ rsub;        // global chunk to fetch
    const uint16_t* gA0 = rnbf + (size_t)(rowA0 + warp * 32 + rsub) * 1024 + csw * 8;
    const uint16_t* gB0 = rnbf + (size_t)(colB0 + warp * 32 + rsub) * 1024 + csw * 8;
    uint16_t* lA0 = &As[warp * 32 * 64];
    uint16_t* lB0 = &Bs[warp * 32 * 64];

    f32x4 acc[4][4];
#pragma unroll
    for (int a = 0; a < 4; ++a)
#pragma unroll
        for (int b = 0; b < 4; ++b) acc[a][b] = (f32x4){0.f, 0.f, 0.f, 0.f};

    for (int kt = 0; kt < 16; ++kt) {
        __syncthreads();   // previous iteration's ds_reads done (and lbl stores at kt=0)
#pragma unroll
        for (int m = 0; m < 4; ++m) {
            GLD16(gA0 + m * 8192 + kt * 64, lA0 + m * 512);
            GLD16(gB0 + m * 8192 + kt * 64, lB0 + m * 512);
        }
        __syncthreads();   // drains vmcnt(0): LDS tiles ready
#pragma unroll
        for (int s = 0; s < 2; ++s) {
            bf16x8 af[4], bf[4];
#pragma unroll
            for (int ti = 0; ti < 4; ++ti) {
                int rowLoc = wr * 64 + ti * 16 + m_;
                int off = rowLoc * 64 + (((s * 4 + g) ^ (m_ & 7)) * 8);
                af[ti] = __builtin_bit_cast(bf16x8, *(const f32x4*)&As[off]);
            }
#pragma unroll
            for (int tj = 0; tj < 4; ++tj) {
                int colLoc = wc * 64 + tj * 16 + m_;
                int off = colLoc * 64 + (((s * 4 + g) ^ (m_ & 7)) * 8);
                bf[tj] = __builtin_bit_cast(bf16x8, *(const f32x4*)&Bs[off]);
            }
#pragma unroll
            for (int ti = 0; ti < 4; ++ti)
#pragma unroll
                for (int tj = 0; tj < 4; ++tj)
                    acc[ti][tj] = __builtin_amdgcn_mfma_f32_16x16x32_bf16(
                        af[ti], bf[tj], acc[ti][tj], 0, 0, 0);
        }
    }

    // epilogue: C layout col=lane&15, row=(lane>>4)*4+reg
    bool isDiag = (bi == bj);
    int cl = m_;
    float colE[4] = {0.f, 0.f, 0.f, 0.f}, colP[4] = {0.f, 0.f, 0.f, 0.f};
#pragma unroll
    for (int ti = 0; ti < 4; ++ti) {
        int rowLoc = wr * 64 + ti * 16 + g * 4;
        float rE[4] = {0.f, 0.f, 0.f, 0.f}, rP[4] = {0.f, 0.f, 0.f, 0.f};
        int lr[4];
#pragma unroll
        for (int r = 0; r < 4; ++r) lr[r] = lblA[rowLoc + r];
#pragma unroll
        for (int tj = 0; tj < 4; ++tj) {
            int colLoc = wc * 64 + tj * 16 + cl;
            int gCol = colB0 + colLoc;
            int lc = lblB[colLoc];
            f32x4 a = acc[ti][tj];
#pragma unroll
            for (int r = 0; r < 4; ++r) {
                int gRow = rowA0 + rowLoc + r;
                float z = INV_T * a[r];
                float e = __expf(z);
                bool offd = (gRow != gCol);
                if (!offd) e = 0.f;
                rE[r] += e;
                colE[tj] += e;
                if (offd && (lr[r] == lc)) { rP[r] += z; colP[tj] += z; }
            }
        }
#pragma unroll
        for (int r = 0; r < 4; ++r) {
            float v = rE[r], p = rP[r];
#pragma unroll
            for (int msk = 1; msk < 16; msk <<= 1) {
                v += __shfl_xor(v, msk, 64);
                p += __shfl_xor(p, msk, 64);
            }
            if (cl == 0) {
                int gRow = rowA0 + rowLoc + r;
                atomicAdd(&denom[gRow], v);
                atomicAdd(&posS[gRow], p);
            }
        }
    }
    if (!isDiag) {
#pragma unroll
        for (int tj = 0; tj < 4; ++tj) {
            float v = colE[tj], p = colP[tj];
            v += __shfl_xor(v, 16, 64); p += __shfl_xor(p, 16, 64);
            v += __shfl_xor(v, 32, 64); p += __shfl_xor(p, 32, 64);
            if (g == 0) {
                int gCol = colB0 + wc * 64 + tj * 16 + cl;
                atomicAdd(&denom[gCol], v);
                atomicAdd(&posS[gCol], p);
            }
        }
    }
}

// ---------------- finalize: per-row term, double accumulation ----------------
__global__ __launch_bounds__(256) void scl_finalize(const float* __restrict__ denom,
                                                    const float* __restrict__ posS,
                                                    const float* __restrict__ sl,
                                                    const int* __restrict__ labels,
                                                    const int* __restrict__ ccnt,
                                                    const float* __restrict__ csum,
                                                    const float* __restrict__ rnG,
                                                    const int* __restrict__ pwp,
                                                    double* __restrict__ oacc) {
    int i = blockIdx.x * 256 + threadIdx.x;
    int bits = *pwp;
    float pw = (bits >= -(1 << 22) && bits <= (1 << 22)) ? (float)bits : __int_as_float(bits);
    const f32x4* sl4 = (const f32x4*)sl;
    const f32x4* rg4 = (const f32x4*)rnG;
    const f32x4* cs4 = (const f32x4*)csum;
    float dW = 0.f, dS = 0.f;
#pragma unroll
    for (int q = 0; q < 8; ++q) {
        f32x4 s = sl4[i * 8 + q];
        f32x4 c = cs4[q];
        f32x4 r = rg4[i * 8 + q];
        dW += s[0] * c[0] + s[1] * c[1] + s[2] * c[2] + s[3] * c[3];
        dS += s[0] * r[0] + s[1] * r[1] + s[2] * r[2] + s[3] * r[3];
    }
    float W = (float)(ccnt[labels[i]] - 1) + pw * dW;
    float S = posS[i] + pw * INV_T * dS;
    float term = __logf(denom[i]) * W - S;
    double td = (double)term;
#pragma unroll
    for (int m = 1; m < 64; m <<= 1) td += __shfl_xor(td, m, 64);
    __shared__ double wsum[4];
    if ((threadIdx.x & 63) == 0) wsum[threadIdx.x >> 6] = td;
    __syncthreads();
    if (threadIdx.x == 0) atomicAdd(oacc, wsum[0] + wsum[1] + wsum[2] + wsum[3]);
}

__global__ void scl_final(const double* __restrict__ oacc, float* __restrict__ out) {
    out[0] = (float)(oacc[0] * (1.0 / 4096.0));
}

// ---------------------------------------------------------------------------
extern "C" void kernel_launch(void* const* d_in, const int* in_sizes, int n_in,
                              void* d_out, int out_size, void* d_ws, size_t ws_size,
                              hipStream_t stream) {
    const float* rep = (const float*)d_in[0];
    const float* sl = (const float*)d_in[1];
    const int* labels = (const int*)d_in[2];
    const int* pwp = (const int*)d_in[3];

    char* ws = (char*)d_ws;
    uint16_t* rnbf = (uint16_t*)(ws + OFF_RNBF);
    float* denom = (float*)(ws + OFF_DENOM);
    float* posS = (float*)(ws + OFF_POSS);
    float* G = (float*)(ws + OFF_G);
    float* csum = (float*)(ws + OFF_CSUM);
    int* ccnt = (int*)(ws + OFF_CCNT);
    double* oacc = (double*)(ws + OFF_OACC);
    float* rnG = (float*)(ws + OFF_RNG);

    hipMemsetAsync(ws + OFF_DENOM, 0, ZERO_BYTES, stream);

    scl_normalize<<<4096, 256, 0, stream>>>(rep, rnbf);
    scl_prep<<<32, 256, 0, stream>>>(sl, labels, csum, ccnt);
    scl_G<<<512, 256, 0, stream>>>(rnbf, sl, G);
    scl_rnG<<<256, 256, 0, stream>>>(rnbf, G, rnG);
    scl_gemm<<<528, 256, 0, stream>>>(rnbf, labels, denom, posS);
    scl_finalize<<<16, 256, 0, stream>>>(denom, posS, sl, labels, ccnt, csum, rnG, pwp, oacc);
    scl_final<<<1, 1, 0, stream>>>(oacc, (float*)d_out);
}

// Round 3
// 132.689 us; speedup vs baseline: 1.3650x; 1.3650x over previous
//
#include <hip/hip_runtime.h>
#include <hip/hip_bf16.h>
#include <stdint.h>

// ---------------------------------------------------------------------------
// SupervisedContrastiveLoss, B=4096, D=1024, C=32, T=0.1, eps=1e-8
// out = (1/B) * [ sum_i (log(denom_i)*W_i - posS_i) - pw*INV_T*||G||_F^2 ]
//   denom_i = sum_{j!=i} exp(Z_ij)   (full Z -> fused fp8 MFMA GEMM, upper-tri)
//   W_i     = (classCount[l_i]-1) + pw*(sl_i . colsum(SL))
//   posS_i  = sum_{j!=i, l_j==l_i} Z_ij
//   G       = rn^T @ SL  [1024x32];  sum_i sl_i.(rn@G)_i == ||G||_F^2
// R2: rn stored as fp8 e4m3 scaled x16 (working set 4.2 MB ~ L2-resident);
//     Z = dot * 10/256. rnG kernel eliminated via ||G||^2. 5 dispatches.
// ---------------------------------------------------------------------------

typedef float f32x4 __attribute__((ext_vector_type(4)));
typedef long i64;

#define INV_T 10.0f
#define Z_SCALE (INV_T / 256.0f)   // both fp8 operands carry x16

#define GLD16(gp, lp)                                                          \
    __builtin_amdgcn_global_load_lds(                                          \
        (const __attribute__((address_space(1))) uint32_t*)(gp),               \
        (__attribute__((address_space(3))) uint32_t*)(lp), 16, 0, 0)

// workspace layout (bytes)
#define OFF_RNF8  0                         // 4096*1024*1 = 4194304
#define OFF_DENOM 4194304                   // 4096*4
#define OFF_POSS  (OFF_DENOM + 16384)
#define OFF_G     (OFF_POSS + 16384)        // 1024*32*4 = 131072
#define OFF_CSUM  (OFF_G + 131072)          // 32*4 (+pad)
#define OFF_CCNT  (OFF_CSUM + 128)
#define OFF_OACC  (OFF_CCNT + 128)          // double
#define OFF_DONE  (OFF_OACC + 16)           // int
#define WS_END    (OFF_DONE + 16)
#define ZERO_BYTES (WS_END - OFF_DENOM)

// ---------------- normalize rows -> fp8(x16)  (+fused prep for blocks>=4096) --
__global__ __launch_bounds__(256) void scl_norm_prep(const float* __restrict__ rep,
                                                     const float* __restrict__ sl,
                                                     const int* __restrict__ labels,
                                                     uint32_t* __restrict__ rnf8,
                                                     float* __restrict__ csum,
                                                     int* __restrict__ ccnt) {
    int b = blockIdx.x;
    int t = threadIdx.x;
    if (b < 4096) {
        int row = b;
        const float4* src = reinterpret_cast<const float4*>(rep + (size_t)row * 1024);
        float4 v = src[t];
        float s = v.x * v.x + v.y * v.y + v.z * v.z + v.w * v.w;
#pragma unroll
        for (int m = 1; m < 64; m <<= 1) s += __shfl_xor(s, m, 64);
        __shared__ float red[4];
        if ((t & 63) == 0) red[t >> 6] = s;
        __syncthreads();
        s = red[0] + red[1] + red[2] + red[3];
        float nf = 16.0f / fmaxf(sqrtf(s), 1e-8f);   // x16 into fp8 normal range
        int p = 0;
        p = __builtin_amdgcn_cvt_pk_fp8_f32(v.x * nf, v.y * nf, p, false);
        p = __builtin_amdgcn_cvt_pk_fp8_f32(v.z * nf, v.w * nf, p, true);
        rnf8[row * 256 + t] = (uint32_t)p;
    } else {
        // prep: colsum of soft_labels + class histogram (32 blocks x 128 rows)
        __shared__ float part[8][32];
        __shared__ int bins[32];
        int bb = b - 4096;
        if (t < 32) bins[t] = 0;
        __syncthreads();
        if (t < 128) atomicAdd(&bins[labels[bb * 128 + t]], 1);
        int c = t & 31, rg = t >> 5;
        float s = 0.f;
#pragma unroll 4
        for (int k = 0; k < 16; ++k) {
            int i = bb * 128 + rg * 16 + k;
            s += sl[i * 32 + c];
        }
        part[rg][c] = s;
        __syncthreads();
        if (t < 32) {
            float tot = 0.f;
#pragma unroll
            for (int g = 0; g < 8; ++g) tot += part[g][t];
            atomicAdd(&csum[t], tot);
            atomicAdd(&ccnt[t], bins[t]);
        }
    }
}

// ---------------- G = rn^T @ SL  [1024 x 32], coalesced fp8 reads ----------------
// grid: 16 d-blocks (64 d) x 32 k-splits (128 rows) = 512 blocks
__global__ __launch_bounds__(256) void scl_G(const uint8_t* __restrict__ rnf8,
                                             const float* __restrict__ sl,
                                             float* __restrict__ G) {
    int t = threadIdx.x;
    int dblk = blockIdx.x & 15, ks = blockIdx.x >> 4;
    int dq = t >> 5, c = t & 31;
    int d0 = dblk * 64 + dq * 8;
    float acc[8];
#pragma unroll
    for (int j = 0; j < 8; ++j) acc[j] = 0.f;
    int i0 = ks * 128;
#pragma unroll 4
    for (int k = 0; k < 128; ++k) {
        int i = i0 + k;
        uint2 rv = *(const uint2*)&rnf8[(size_t)i * 1024 + d0];
        float sv = sl[i * 32 + c];
        acc[0] += __builtin_amdgcn_cvt_f32_fp8((int)rv.x, 0) * sv;
        acc[1] += __builtin_amdgcn_cvt_f32_fp8((int)rv.x, 1) * sv;
        acc[2] += __builtin_amdgcn_cvt_f32_fp8((int)rv.x, 2) * sv;
        acc[3] += __builtin_amdgcn_cvt_f32_fp8((int)rv.x, 3) * sv;
        acc[4] += __builtin_amdgcn_cvt_f32_fp8((int)rv.y, 0) * sv;
        acc[5] += __builtin_amdgcn_cvt_f32_fp8((int)rv.y, 1) * sv;
        acc[6] += __builtin_amdgcn_cvt_f32_fp8((int)rv.y, 2) * sv;
        acc[7] += __builtin_amdgcn_cvt_f32_fp8((int)rv.y, 3) * sv;
    }
#pragma unroll
    for (int j = 0; j < 8; ++j)
        atomicAdd(&G[(d0 + j) * 32 + c], acc[j] * 0.0625f);  // undo x16
}

// ---------------- main fused GEMM (fp8): rowsum/colsum of exp(Z), pos*Z ----------
// 128x128 tiles, upper-tri (528 blocks). global_load_lds 16B staging, even-XOR
// swizzle on the GLOBAL side (16B granularity), ds_read_b64 frags (2-way max).
__global__ __launch_bounds__(256) void scl_gemm(const uint8_t* __restrict__ rnf8,
                                                const int* __restrict__ labels,
                                                float* __restrict__ denom,
                                                float* __restrict__ posS) {
    __shared__ __align__(16) uint8_t As[128 * 64];
    __shared__ __align__(16) uint8_t Bs[128 * 64];
    __shared__ int lblA[128], lblB[128];

    int L = blockIdx.x;
    int bi = 0, rem = L;
    while (rem >= 32 - bi) { rem -= 32 - bi; ++bi; }
    int bj = bi + rem;
    int rowA0 = bi * 128, colB0 = bj * 128;

    int tid = threadIdx.x;
    if (tid < 128) {
        lblA[tid] = labels[rowA0 + tid];
        lblB[tid] = labels[colB0 + tid];
    }

    int lane = tid & 63, warp = tid >> 6;
    int wr = warp >> 1, wc = warp & 1;
    int m_ = lane & 15, g = lane >> 4;

    // staging: wave stages 32 rows (2 rounds of 16); lane covers row l>>2,
    // 16B-chunk l&3, fetching global chunk (l&3)^((l>>3)&3)  [even-XOR]
    int r4 = lane >> 2;
    int csw = (lane & 3) ^ ((lane >> 3) & 3);
    const uint8_t* gA0 = rnf8 + (size_t)(rowA0 + warp * 32 + r4) * 1024 + csw * 16;
    const uint8_t* gB0 = rnf8 + (size_t)(colB0 + warp * 32 + r4) * 1024 + csw * 16;

    f32x4 acc[4][4];
#pragma unroll
    for (int a = 0; a < 4; ++a)
#pragma unroll
        for (int b = 0; b < 4; ++b) acc[a][b] = (f32x4){0.f, 0.f, 0.f, 0.f};

    for (int kt = 0; kt < 16; ++kt) {
        __syncthreads();
        GLD16(gA0 + kt * 64,          &As[(warp * 32) * 64]);
        GLD16(gA0 + kt * 64 + 16384,  &As[(warp * 32 + 16) * 64]);   // +16 rows
        GLD16(gB0 + kt * 64,          &Bs[(warp * 32) * 64]);
        GLD16(gB0 + kt * 64 + 16384,  &Bs[(warp * 32 + 16) * 64]);
        __syncthreads();
#pragma unroll
        for (int s = 0; s < 2; ++s) {
            i64 af[4], bf[4];
#pragma unroll
            for (int ti = 0; ti < 4; ++ti) {
                int rowLoc = wr * 64 + ti * 16 + m_;
                af[ti] = *(const i64*)&As[rowLoc * 64 + (((s * 4 + g) ^ (m_ & 6)) * 8)];
            }
#pragma unroll
            for (int tj = 0; tj < 4; ++tj) {
                int colLoc = wc * 64 + tj * 16 + m_;
                bf[tj] = *(const i64*)&Bs[colLoc * 64 + (((s * 4 + g) ^ (m_ & 6)) * 8)];
            }
#pragma unroll
            for (int ti = 0; ti < 4; ++ti)
#pragma unroll
                for (int tj = 0; tj < 4; ++tj)
                    acc[ti][tj] = __builtin_amdgcn_mfma_f32_16x16x32_fp8_fp8(
                        af[ti], bf[tj], acc[ti][tj], 0, 0, 0);
        }
    }

    // epilogue: C layout col=lane&15, row=(lane>>4)*4+reg
    bool isDiag = (bi == bj);
    int cl = m_;
    float colE[4] = {0.f, 0.f, 0.f, 0.f}, colP[4] = {0.f, 0.f, 0.f, 0.f};
#pragma unroll
    for (int ti = 0; ti < 4; ++ti) {
        int rowLoc = wr * 64 + ti * 16 + g * 4;
        float rE[4] = {0.f, 0.f, 0.f, 0.f}, rP[4] = {0.f, 0.f, 0.f, 0.f};
        int lr[4];
#pragma unroll
        for (int r = 0; r < 4; ++r) lr[r] = lblA[rowLoc + r];
#pragma unroll
        for (int tj = 0; tj < 4; ++tj) {
            int colLoc = wc * 64 + tj * 16 + cl;
            int gCol = colB0 + colLoc;
            int lc = lblB[colLoc];
            f32x4 a = acc[ti][tj];
#pragma unroll
            for (int r = 0; r < 4; ++r) {
                int gRow = rowA0 + rowLoc + r;
                float z = Z_SCALE * a[r];
                float e = __expf(z);
                bool offd = (gRow != gCol);
                if (!offd) e = 0.f;
                rE[r] += e;
                colE[tj] += e;
                if (offd && (lr[r] == lc)) { rP[r] += z; colP[tj] += z; }
            }
        }
#pragma unroll
        for (int r = 0; r < 4; ++r) {
            float v = rE[r], p = rP[r];
#pragma unroll
            for (int msk = 1; msk < 16; msk <<= 1) {
                v += __shfl_xor(v, msk, 64);
                p += __shfl_xor(p, msk, 64);
            }
            if (cl == 0) {
                int gRow = rowA0 + rowLoc + r;
                atomicAdd(&denom[gRow], v);
                atomicAdd(&posS[gRow], p);
            }
        }
    }
    if (!isDiag) {
#pragma unroll
        for (int tj = 0; tj < 4; ++tj) {
            float v = colE[tj], p = colP[tj];
            v += __shfl_xor(v, 16, 64); p += __shfl_xor(p, 16, 64);
            v += __shfl_xor(v, 32, 64); p += __shfl_xor(p, 32, 64);
            if (g == 0) {
                int gCol = colB0 + wc * 64 + tj * 16 + cl;
                atomicAdd(&denom[gCol], v);
                atomicAdd(&posS[gCol], p);
            }
        }
    }
}

// ---------------- finalize: rows (blocks 0..15) + ||G||^2 (block 16) + output ----
__global__ __launch_bounds__(256) void scl_finalize(const float* __restrict__ denom,
                                                    const float* __restrict__ posS,
                                                    const float* __restrict__ sl,
                                                    const int* __restrict__ labels,
                                                    const int* __restrict__ ccnt,
                                                    const float* __restrict__ csum,
                                                    const float* __restrict__ G,
                                                    const int* __restrict__ pwp,
                                                    double* __restrict__ oacc,
                                                    int* __restrict__ done,
                                                    float* __restrict__ out) {
    int t = threadIdx.x;
    int bits = *pwp;
    float pw = (bits >= -(1 << 22) && bits <= (1 << 22)) ? (float)bits : __int_as_float(bits);
    __shared__ double wsum[4];
    double contrib = 0.0;

    if (blockIdx.x < 16) {
        int i = blockIdx.x * 256 + t;
        const f32x4* sl4 = (const f32x4*)sl;
        const f32x4* cs4 = (const f32x4*)csum;
        float dW = 0.f;
#pragma unroll
        for (int q = 0; q < 8; ++q) {
            f32x4 s = sl4[i * 8 + q];
            f32x4 c = cs4[q];
            dW += s[0] * c[0] + s[1] * c[1] + s[2] * c[2] + s[3] * c[3];
        }
        float W = (float)(ccnt[labels[i]] - 1) + pw * dW;
        float term = __logf(denom[i]) * W - posS[i];
        double td = (double)term;
#pragma unroll
        for (int m = 1; m < 64; m <<= 1) td += __shfl_xor(td, m, 64);
        if ((t & 63) == 0) wsum[t >> 6] = td;
        __syncthreads();
        contrib = wsum[0] + wsum[1] + wsum[2] + wsum[3];
    } else {
        // block 16: -pw*INV_T*||G||^2
        const f32x4* G4 = (const f32x4*)G;
        float gs = 0.f;
#pragma unroll
        for (int q = 0; q < 32; ++q) {
            f32x4 v = G4[q * 256 + t];
            gs += v[0] * v[0] + v[1] * v[1] + v[2] * v[2] + v[3] * v[3];
        }
        double gd = (double)gs;
#pragma unroll
        for (int m = 1; m < 64; m <<= 1) gd += __shfl_xor(gd, m, 64);
        if ((t & 63) == 0) wsum[t >> 6] = gd;
        __syncthreads();
        contrib = -(double)(pw * INV_T) * (wsum[0] + wsum[1] + wsum[2] + wsum[3]);
    }

    if (t == 0) {
        atomicAdd(oacc, contrib);
        __threadfence();
        int old = atomicAdd(done, 1);
        if (old == 16) {  // last of 17 blocks
            double tot = atomicAdd(oacc, 0.0);  // coherent read
            out[0] = (float)(tot * (1.0 / 4096.0));
        }
    }
}

// ---------------------------------------------------------------------------
extern "C" void kernel_launch(void* const* d_in, const int* in_sizes, int n_in,
                              void* d_out, int out_size, void* d_ws, size_t ws_size,
                              hipStream_t stream) {
    const float* rep = (const float*)d_in[0];
    const float* sl = (const float*)d_in[1];
    const int* labels = (const int*)d_in[2];
    const int* pwp = (const int*)d_in[3];

    char* ws = (char*)d_ws;
    uint8_t* rnf8 = (uint8_t*)(ws + OFF_RNF8);
    float* denom = (float*)(ws + OFF_DENOM);
    float* posS = (float*)(ws + OFF_POSS);
    float* G = (float*)(ws + OFF_G);
    float* csum = (float*)(ws + OFF_CSUM);
    int* ccnt = (int*)(ws + OFF_CCNT);
    double* oacc = (double*)(ws + OFF_OACC);
    int* done = (int*)(ws + OFF_DONE);

    hipMemsetAsync(ws + OFF_DENOM, 0, ZERO_BYTES, stream);

    scl_norm_prep<<<4128, 256, 0, stream>>>(rep, sl, labels, (uint32_t*)rnf8, csum, ccnt);
    scl_G<<<512, 256, 0, stream>>>(rnf8, sl, G);
    scl_gemm<<<528, 256, 0, stream>>>(rnf8, labels, denom, posS);
    scl_finalize<<<17, 256, 0, stream>>>(denom, posS, sl, labels, ccnt, csum, G, pwp,
                                         oacc, done, (float*)d_out);
}

// Round 4
// 118.276 us; speedup vs baseline: 1.5313x; 1.1219x over previous
//
#include <hip/hip_runtime.h>
#include <hip/hip_bf16.h>
#include <stdint.h>

// ---------------------------------------------------------------------------
// SupervisedContrastiveLoss, B=4096, D=1024, C=32, T=0.1, eps=1e-8
// out = (1/B) * [ sum_i (log(denom_i)*W_i - posS_i) - pw*INV_T*||G||_F^2 ]
// R4: 3 dispatches.
//   D1: normalize->fp8(x16) + prep partials (csum/ccnt per 128-row slab) + zero
//   D2: fused grid = 528 gemm tiles (upper-tri, fp8 MFMA, b128 k-permuted
//       frags) + 512 G-GEMM blocks + 16 W blocks  (concurrent, m114 overlap)
//   D3: finalize (9 blocks, done-counter writes out)
// ---------------------------------------------------------------------------

typedef float f32x4 __attribute__((ext_vector_type(4)));
typedef long i64;

#define INV_T 10.0f
#define Z_SCALE (INV_T / 256.0f)   // both fp8 operands carry x16

#define GLD16(gp, lp)                                                          \
    __builtin_amdgcn_global_load_lds(                                          \
        (const __attribute__((address_space(1))) uint32_t*)(gp),               \
        (__attribute__((address_space(3))) uint32_t*)(lp), 16, 0, 0)

// workspace layout (bytes)
#define OFF_RNF8  0                         // 4096*1024 = 4194304
#define OFF_DENOM 4194304                   // 4096*4
#define OFF_POSS  (OFF_DENOM + 16384)
#define OFF_G     (OFF_POSS + 16384)        // 1024*32*4 = 131072
#define OFF_OACC  (OFF_G + 131072)          // double
#define OFF_DONE  (OFF_OACC + 16)           // int
#define ZERO_SPAN 167936                    // 41*4096 >= 163904 (zeroed region)
#define OFF_CSP   (OFF_DENOM + ZERO_SPAN)   // 32*32*4 colsum partials
#define OFF_CCP   (OFF_CSP + 4096)          // 32*32*4 histogram partials
#define OFF_W     (OFF_CCP + 4096)          // 4096*4

// ---------------- D1: normalize -> fp8(x16) | prep partials | zero ----------
__global__ __launch_bounds__(256) void scl_stage1(const float* __restrict__ rep,
                                                  const float* __restrict__ sl,
                                                  const int* __restrict__ labels,
                                                  uint32_t* __restrict__ rnf8,
                                                  float* __restrict__ cs_part,
                                                  int* __restrict__ cc_part,
                                                  char* __restrict__ zbase) {
    int b = blockIdx.x;
    int t = threadIdx.x;
    if (b < 4096) {
        int row = b;
        const float4* src = reinterpret_cast<const float4*>(rep + (size_t)row * 1024);
        float4 v = src[t];
        float s = v.x * v.x + v.y * v.y + v.z * v.z + v.w * v.w;
#pragma unroll
        for (int m = 1; m < 64; m <<= 1) s += __shfl_xor(s, m, 64);
        __shared__ float red[4];
        if ((t & 63) == 0) red[t >> 6] = s;
        __syncthreads();
        s = red[0] + red[1] + red[2] + red[3];
        float nf = 16.0f / fmaxf(sqrtf(s), 1e-8f);   // x16 into fp8 normal range
        int p = 0;
        p = __builtin_amdgcn_cvt_pk_fp8_f32(v.x * nf, v.y * nf, p, false);
        p = __builtin_amdgcn_cvt_pk_fp8_f32(v.z * nf, v.w * nf, p, true);
        rnf8[row * 256 + t] = (uint32_t)p;
    } else if (b < 4128) {
        // prep partials: colsum of soft_labels + class histogram (128 rows/slab)
        __shared__ float part[8][32];
        __shared__ int bins[32];
        int bb = b - 4096;
        if (t < 32) bins[t] = 0;
        __syncthreads();
        if (t < 128) atomicAdd(&bins[labels[bb * 128 + t]], 1);
        int c = t & 31, rg = t >> 5;
        float s = 0.f;
#pragma unroll 4
        for (int k = 0; k < 16; ++k) {
            int i = bb * 128 + rg * 16 + k;
            s += sl[i * 32 + c];
        }
        part[rg][c] = s;
        __syncthreads();
        if (t < 32) {
            float tot = 0.f;
#pragma unroll
            for (int g = 0; g < 8; ++g) tot += part[g][t];
            cs_part[bb * 32 + t] = tot;
            cc_part[bb * 32 + t] = bins[t];
        }
    } else {
        // zero blocks: denom/posS/G/oacc/done (consumed in D2/D3)
        int zb = b - 4128;
        *(uint4*)(zbase + (size_t)zb * 4096 + t * 16) = (uint4){0, 0, 0, 0};
    }
}

// ---------------- D2: fused gemm + G + W ------------------------------------
__global__ __launch_bounds__(256) void scl_main(const uint8_t* __restrict__ rnf8,
                                                const float* __restrict__ sl,
                                                const int* __restrict__ labels,
                                                const float* __restrict__ cs_part,
                                                const int* __restrict__ cc_part,
                                                const int* __restrict__ pwp,
                                                float* __restrict__ denom,
                                                float* __restrict__ posS,
                                                float* __restrict__ G,
                                                float* __restrict__ W) {
    int tid = threadIdx.x;

    if (blockIdx.x >= 528) {
        if (blockIdx.x < 1040) {
            // ---- G = rn^T @ SL : 16 d-blocks x 32 k-splits ----
            int idx = blockIdx.x - 528;
            int dblk = idx & 15, ks = idx >> 4;
            int dq = tid >> 5, c = tid & 31;
            int d0 = dblk * 64 + dq * 8;
            float acc[8];
#pragma unroll
            for (int j = 0; j < 8; ++j) acc[j] = 0.f;
            int i0 = ks * 128;
#pragma unroll 4
            for (int k = 0; k < 128; ++k) {
                int i = i0 + k;
                uint2 rv = *(const uint2*)&rnf8[(size_t)i * 1024 + d0];
                float sv = sl[i * 32 + c];
                acc[0] += __builtin_amdgcn_cvt_f32_fp8((int)rv.x, 0) * sv;
                acc[1] += __builtin_amdgcn_cvt_f32_fp8((int)rv.x, 1) * sv;
                acc[2] += __builtin_amdgcn_cvt_f32_fp8((int)rv.x, 2) * sv;
                acc[3] += __builtin_amdgcn_cvt_f32_fp8((int)rv.x, 3) * sv;
                acc[4] += __builtin_amdgcn_cvt_f32_fp8((int)rv.y, 0) * sv;
                acc[5] += __builtin_amdgcn_cvt_f32_fp8((int)rv.y, 1) * sv;
                acc[6] += __builtin_amdgcn_cvt_f32_fp8((int)rv.y, 2) * sv;
                acc[7] += __builtin_amdgcn_cvt_f32_fp8((int)rv.y, 3) * sv;
            }
#pragma unroll
            for (int j = 0; j < 8; ++j)
                atomicAdd(&G[(d0 + j) * 32 + c], acc[j] * 0.0625f);  // undo x16
        } else {
            // ---- W[i] = (ccnt[l_i]-1) + pw*(sl_i . csum) : 16 blocks x 256 rows
            __shared__ __align__(16) float css[32];
            __shared__ int ccs[32];
            if (tid < 32) {
                float s = 0.f; int n = 0;
#pragma unroll
                for (int b = 0; b < 32; ++b) { s += cs_part[b * 32 + tid]; n += cc_part[b * 32 + tid]; }
                css[tid] = s; ccs[tid] = n;
            }
            __syncthreads();
            int bits = *pwp;
            float pw = (bits >= -(1 << 22) && bits <= (1 << 22)) ? (float)bits
                                                                 : __int_as_float(bits);
            int i = (blockIdx.x - 1040) * 256 + tid;
            const f32x4* sl4 = (const f32x4*)sl;
            const f32x4* cs4 = (const f32x4*)css;
            float dW = 0.f;
#pragma unroll
            for (int q = 0; q < 8; ++q) {
                f32x4 s = sl4[i * 8 + q];
                f32x4 c = cs4[q];
                dW += s[0] * c[0] + s[1] * c[1] + s[2] * c[2] + s[3] * c[3];
            }
            W[i] = (float)(ccs[labels[i]] - 1) + pw * dW;
        }
        return;
    }

    // ---- main fp8 GEMM tile: rowsum/colsum of exp(Z), pos*Z ----
    __shared__ __align__(16) uint8_t As[128 * 64];
    __shared__ __align__(16) uint8_t Bs[128 * 64];
    __shared__ int lblA[128], lblB[128];

    int L = blockIdx.x;
    int bi = 0, rem = L;
    while (rem >= 32 - bi) { rem -= 32 - bi; ++bi; }
    int bj = bi + rem;
    int rowA0 = bi * 128, colB0 = bj * 128;

    if (tid < 128) {
        lblA[tid] = labels[rowA0 + tid];
        lblB[tid] = labels[colB0 + tid];
    }

    int lane = tid & 63, warp = tid >> 6;
    int wr = warp >> 1, wc = warp & 1;
    int m_ = lane & 15, g = lane >> 4;

    // staging: lane l -> row l>>2, LDS slot l&3; fetch global chunk (l&3)^((l>>3)&3)
    int r4 = lane >> 2;
    int csw = (lane & 3) ^ ((lane >> 3) & 3);
    const uint8_t* gA0 = rnf8 + (size_t)(rowA0 + warp * 32 + r4) * 1024 + csw * 16;
    const uint8_t* gB0 = rnf8 + (size_t)(colB0 + warp * 32 + r4) * 1024 + csw * 16;

    f32x4 acc[4][4];
#pragma unroll
    for (int a = 0; a < 4; ++a)
#pragma unroll
        for (int b = 0; b < 4; ++b) acc[a][b] = (f32x4){0.f, 0.f, 0.f, 0.f};

    // frag LDS offset: global 16B-chunk g of row r lives at slot g^((r>>1)&3)
    int fsw = (g ^ ((m_ >> 1) & 3)) * 16;

    for (int kt = 0; kt < 16; ++kt) {
        __syncthreads();
        GLD16(gA0 + kt * 64,         &As[(warp * 32) * 64]);
        GLD16(gA0 + kt * 64 + 16384, &As[(warp * 32 + 16) * 64]);
        GLD16(gB0 + kt * 64,         &Bs[(warp * 32) * 64]);
        GLD16(gB0 + kt * 64 + 16384, &Bs[(warp * 32 + 16) * 64]);
        __syncthreads();
        // one b128 per tile: k-permuted pair of fp8 frags (s=0: bytes 0-7, s=1: 8-15)
        f32x4 aq[4], bq[4];
#pragma unroll
        for (int ti = 0; ti < 4; ++ti) {
            int rowLoc = wr * 64 + ti * 16 + m_;
            aq[ti] = *(const f32x4*)&As[rowLoc * 64 + fsw];
        }
#pragma unroll
        for (int tj = 0; tj < 4; ++tj) {
            int colLoc = wc * 64 + tj * 16 + m_;
            bq[tj] = *(const f32x4*)&Bs[colLoc * 64 + fsw];
        }
#pragma unroll
        for (int s = 0; s < 2; ++s)
#pragma unroll
            for (int ti = 0; ti < 4; ++ti)
#pragma unroll
                for (int tj = 0; tj < 4; ++tj) {
                    i64 a = ((const i64*)&aq[ti])[s];
                    i64 b = ((const i64*)&bq[tj])[s];
                    acc[ti][tj] = __builtin_amdgcn_mfma_f32_16x16x32_fp8_fp8(
                        a, b, acc[ti][tj], 0, 0, 0);
                }
    }

    // epilogue: C layout col=lane&15, row=(lane>>4)*4+reg
    bool isDiag = (bi == bj);
    int cl = m_;
    float colE[4] = {0.f, 0.f, 0.f, 0.f}, colP[4] = {0.f, 0.f, 0.f, 0.f};
#pragma unroll
    for (int ti = 0; ti < 4; ++ti) {
        int rowLoc = wr * 64 + ti * 16 + g * 4;
        float rE[4] = {0.f, 0.f, 0.f, 0.f}, rP[4] = {0.f, 0.f, 0.f, 0.f};
        int lr[4];
#pragma unroll
        for (int r = 0; r < 4; ++r) lr[r] = lblA[rowLoc + r];
#pragma unroll
        for (int tj = 0; tj < 4; ++tj) {
            int colLoc = wc * 64 + tj * 16 + cl;
            int gCol = colB0 + colLoc;
            int lc = lblB[colLoc];
            f32x4 a = acc[ti][tj];
#pragma unroll
            for (int r = 0; r < 4; ++r) {
                int gRow = rowA0 + rowLoc + r;
                float z = Z_SCALE * a[r];
                float e = __expf(z);
                bool offd = (gRow != gCol);
                if (!offd) e = 0.f;
                rE[r] += e;
                colE[tj] += e;
                if (offd && (lr[r] == lc)) { rP[r] += z; colP[tj] += z; }
            }
        }
#pragma unroll
        for (int r = 0; r < 4; ++r) {
            float v = rE[r], p = rP[r];
#pragma unroll
            for (int msk = 1; msk < 16; msk <<= 1) {
                v += __shfl_xor(v, msk, 64);
                p += __shfl_xor(p, msk, 64);
            }
            if (cl == 0) {
                int gRow = rowA0 + rowLoc + r;
                atomicAdd(&denom[gRow], v);
                atomicAdd(&posS[gRow], p);
            }
        }
    }
    if (!isDiag) {
#pragma unroll
        for (int tj = 0; tj < 4; ++tj) {
            float v = colE[tj], p = colP[tj];
            v += __shfl_xor(v, 16, 64); p += __shfl_xor(p, 16, 64);
            v += __shfl_xor(v, 32, 64); p += __shfl_xor(p, 32, 64);
            if (g == 0) {
                int gCol = colB0 + wc * 64 + tj * 16 + cl;
                atomicAdd(&denom[gCol], v);
                atomicAdd(&posS[gCol], p);
            }
        }
    }
}

// ---------------- D3: finalize (8 row-blocks + 1 G-block), done-counter -----
__global__ __launch_bounds__(256) void scl_finalize(const float* __restrict__ denom,
                                                    const float* __restrict__ posS,
                                                    const float* __restrict__ W,
                                                    const float* __restrict__ G,
                                                    const int* __restrict__ pwp,
                                                    double* __restrict__ oacc,
                                                    int* __restrict__ done,
                                                    float* __restrict__ out) {
    int t = threadIdx.x;
    __shared__ double wsum[4];
    double contrib = 0.0;

    if (blockIdx.x < 8) {
        int i0 = blockIdx.x * 512 + t;
        float t0 = __logf(denom[i0]) * W[i0] - posS[i0];
        float t1 = __logf(denom[i0 + 256]) * W[i0 + 256] - posS[i0 + 256];
        double td = (double)t0 + (double)t1;
#pragma unroll
        for (int m = 1; m < 64; m <<= 1) td += __shfl_xor(td, m, 64);
        if ((t & 63) == 0) wsum[t >> 6] = td;
        __syncthreads();
        contrib = wsum[0] + wsum[1] + wsum[2] + wsum[3];
    } else {
        int bits = *pwp;
        float pw = (bits >= -(1 << 22) && bits <= (1 << 22)) ? (float)bits
                                                             : __int_as_float(bits);
        const f32x4* G4 = (const f32x4*)G;
        float gs = 0.f;
#pragma unroll
        for (int q = 0; q < 32; ++q) {
            f32x4 v = G4[q * 256 + t];
            gs += v[0] * v[0] + v[1] * v[1] + v[2] * v[2] + v[3] * v[3];
        }
        double gd = (double)gs;
#pragma unroll
        for (int m = 1; m < 64; m <<= 1) gd += __shfl_xor(gd, m, 64);
        if ((t & 63) == 0) wsum[t >> 6] = gd;
        __syncthreads();
        contrib = -(double)(pw * INV_T) * (wsum[0] + wsum[1] + wsum[2] + wsum[3]);
    }

    if (t == 0) {
        atomicAdd(oacc, contrib);
        __threadfence();
        int old = atomicAdd(done, 1);
        if (old == 8) {  // last of 9 blocks
            double tot = atomicAdd(oacc, 0.0);  // coherent read
            out[0] = (float)(tot * (1.0 / 4096.0));
        }
    }
}

// ---------------------------------------------------------------------------
extern "C" void kernel_launch(void* const* d_in, const int* in_sizes, int n_in,
                              void* d_out, int out_size, void* d_ws, size_t ws_size,
                              hipStream_t stream) {
    const float* rep = (const float*)d_in[0];
    const float* sl = (const float*)d_in[1];
    const int* labels = (const int*)d_in[2];
    const int* pwp = (const int*)d_in[3];

    char* ws = (char*)d_ws;
    uint8_t* rnf8 = (uint8_t*)(ws + OFF_RNF8);
    float* denom = (float*)(ws + OFF_DENOM);
    float* posS = (float*)(ws + OFF_POSS);
    float* G = (float*)(ws + OFF_G);
    double* oacc = (double*)(ws + OFF_OACC);
    int* done = (int*)(ws + OFF_DONE);
    float* cs_part = (float*)(ws + OFF_CSP);
    int* cc_part = (int*)(ws + OFF_CCP);
    float* W = (float*)(ws + OFF_W);

    scl_stage1<<<4169, 256, 0, stream>>>(rep, sl, labels, (uint32_t*)rnf8,
                                         cs_part, cc_part, ws + OFF_DENOM);
    scl_main<<<1056, 256, 0, stream>>>(rnf8, sl, labels, cs_part, cc_part, pwp,
                                       denom, posS, G, W);
    scl_finalize<<<9, 256, 0, stream>>>(denom, posS, W, G, pwp, oacc, done,
                                        (float*)d_out);
}